// Round 1
// baseline (458.198 us; speedup 1.0000x reference)
//
#include <hip/hip_runtime.h>
#include <hip/hip_cooperative_groups.h>

namespace cg = cooperative_groups;

// ScRRAMBLe layer, fully fused single cooperative kernel.
// R4 theory: the 292 us was dispatch/boundary overhead (4 dependent dispatches
// at ~15% effective HBM BW while the harness's own 512 MiB fills run at 85%).
// One kernel, 512 blocks x 256 threads (2 blocks/CU, co-resident), grid.sync()
// between phases. Phase 0 zeroes h1/h2 (kills the memset dispatch). Phase 2
// gives each block one core (i = blockIdx.x, loop j=0..3): h1[i] loaded once,
// Wi stream is 256 KiB contiguous per block.
// Compulsory traffic: Wi+Wo (2x128 MiB) + Ci/Cc (2x16 MiB) ~= 44 us @ 6.8 TB/s.

#define N_CORES 512
#define SLOTS 4
#define SLOT_LEN 64
#define CORE_VEC 256                     // SLOTS*SLOT_LEN
#define H_ELEMS (N_CORES * CORE_VEC)     // 131072 floats per h buffer
#define ROW_LEN 2048                     // K*L = 512*4 entries per source row
#define W_CORE (SLOTS * SLOT_LEN * SLOT_LEN)   // 16384 floats per (i,j) weight block

typedef float v4f __attribute__((ext_vector_type(4)));

__device__ __forceinline__ float capped_relu(float v) {
    return fminf(fmaxf(v, 0.0f), 10.0f);
}

__global__ __launch_bounds__(256, 2) void fused(
        const float* __restrict__ x,
        const float* __restrict__ Wi,
        const float* __restrict__ Wo,
        const float* __restrict__ Ci,
        const float* __restrict__ Cc,
        float* __restrict__ h1,
        float* __restrict__ h2,
        float* __restrict__ out) {
    cg::grid_group grid = cg::this_grid();

    const int b   = blockIdx.x;            // 0..511 == core index
    const int tid = threadIdx.x;
    const int t   = tid & 63;              // lane
    const int w   = tid >> 6;              // wave in block (0..3)
    const int g   = t >> 4;
    const int c16 = t & 15;

    __shared__ float ly[SLOT_LEN];

    // ---- phase 0: zero h1 and h2 (grid exactly covers H_ELEMS) ----
    const int gid = b * 256 + tid;
    h1[gid] = 0.0f;
    h2[gid] = 0.0f;
    grid.sync();

    // ---- phase 1: route x through Ci into h1. Wave w owns source row b*4+w.
    // For each nonzero count c at dst kl: h1[kl, lane] += c * x[ij, lane].
    {
        const int row_id = b * SLOTS + w;              // ij in 0..2047
        const float xv = x[row_id * SLOT_LEN + t];
        const v4f* row4 = reinterpret_cast<const v4f*>(Ci + (size_t)row_id * ROW_LEN);
        for (int chunk = 0; chunk < 8; ++chunk) {
            v4f c4 = __builtin_nontemporal_load(row4 + chunk * 64 + t);
            #pragma unroll
            for (int q = 0; q < 4; ++q) {
                float cq = c4[q];
                unsigned long long m = __ballot(cq != 0.0f);
                while (m) {
                    int L = __ffsll(m) - 1;
                    m &= m - 1;
                    float c = __shfl(cq, L, 64);
                    int dst = chunk * 256 + L * 4 + q;  // kl index
                    atomicAdd(h1 + dst * SLOT_LEN + t, c * xv);
                }
            }
        }
    }
    grid.sync();

    // ---- phase 2: y1[b,j,:] = act(Wi[b,j]·h1[b]); scatter through Cc into h2.
    // h1[b] hoisted out of the j-loop (loaded once per block instead of 4x).
    {
        v4f hk[SLOTS];
        #pragma unroll
        for (int k = 0; k < SLOTS; ++k)
            hk[k] = *reinterpret_cast<const v4f*>(h1 + b * CORE_VEC + k * SLOT_LEN + c16 * 4);

        for (int j = 0; j < SLOTS; ++j) {
            const int p = b * SLOTS + j;
            // prefetch this wave's 2 chunks of the Cc routing row (overlaps W stream)
            const v4f* row4 = reinterpret_cast<const v4f*>(Cc + (size_t)p * ROW_LEN);
            v4f cpre[2];
            #pragma unroll
            for (int cc = 0; cc < 2; ++cc)
                cpre[cc] = __builtin_nontemporal_load(row4 + (w * 2 + cc) * 64 + t);

            const float* Wb = Wi + (size_t)p * W_CORE;
            #pragma unroll
            for (int rr = 0; rr < 4; ++rr) {
                const int r = w * 4 + rr;              // 0..15
                float pacc = 0.0f;
                #pragma unroll
                for (int k = 0; k < SLOTS; ++k) {
                    v4f a = __builtin_nontemporal_load(
                        reinterpret_cast<const v4f*>(Wb + k * (SLOT_LEN * SLOT_LEN)
                                                     + r * 256 + t * 4));
                    pacc += a.x * hk[k].x + a.y * hk[k].y + a.z * hk[k].z + a.w * hk[k].w;
                }
                pacc += __shfl_xor(pacc, 1);
                pacc += __shfl_xor(pacc, 2);
                pacc += __shfl_xor(pacc, 4);
                pacc += __shfl_xor(pacc, 8);
                if (c16 == 0) ly[r * 4 + g] = capped_relu(pacc);
            }
            __syncthreads();
            const float yv = ly[t];
            #pragma unroll
            for (int cc = 0; cc < 2; ++cc) {
                const int chunk = w * 2 + cc;
                #pragma unroll
                for (int q = 0; q < 4; ++q) {
                    float cq = cpre[cc][q];
                    unsigned long long m = __ballot(cq != 0.0f);
                    while (m) {
                        int L = __ffsll(m) - 1;
                        m &= m - 1;
                        float c = __shfl(cq, L, 64);
                        int dst = chunk * 256 + L * 4 + q;
                        atomicAdd(h2 + dst * SLOT_LEN + t, c * yv);
                    }
                }
            }
            __syncthreads();   // guard ly before next j iteration overwrites it
        }
    }
    grid.sync();

    // ---- phase 3: out[b,j,:] = act(Wo[b,j]·h2[b]) ----
    {
        v4f hk[SLOTS];
        #pragma unroll
        for (int k = 0; k < SLOTS; ++k)
            hk[k] = *reinterpret_cast<const v4f*>(h2 + b * CORE_VEC + k * SLOT_LEN + c16 * 4);

        for (int j = 0; j < SLOTS; ++j) {
            const float* Wb = Wo + (size_t)(b * SLOTS + j) * W_CORE;
            #pragma unroll
            for (int rr = 0; rr < 4; ++rr) {
                const int r = w * 4 + rr;
                float pacc = 0.0f;
                #pragma unroll
                for (int k = 0; k < SLOTS; ++k) {
                    v4f a = __builtin_nontemporal_load(
                        reinterpret_cast<const v4f*>(Wb + k * (SLOT_LEN * SLOT_LEN)
                                                     + r * 256 + t * 4));
                    pacc += a.x * hk[k].x + a.y * hk[k].y + a.z * hk[k].z + a.w * hk[k].w;
                }
                pacc += __shfl_xor(pacc, 1);
                pacc += __shfl_xor(pacc, 2);
                pacc += __shfl_xor(pacc, 4);
                pacc += __shfl_xor(pacc, 8);
                if (c16 == 0)
                    out[(b * SLOTS + j) * SLOT_LEN + r * 4 + g] = capped_relu(pacc);
            }
        }
    }
}

extern "C" void kernel_launch(void* const* d_in, const int* in_sizes, int n_in,
                              void* d_out, int out_size, void* d_ws, size_t ws_size,
                              hipStream_t stream) {
    const float* x  = (const float*)d_in[0];   // [131072]
    const float* Wi = (const float*)d_in[1];   // [512,4,4,64,64]
    const float* Wo = (const float*)d_in[2];   // [512,4,4,64,64]
    const float* Ci = (const float*)d_in[3];   // [512,4,512,4]
    const float* Cc = (const float*)d_in[4];   // [512,4,512,4]
    float* out = (float*)d_out;                // [512,4,64]

    float* h1 = (float*)d_ws;            // [131072]
    float* h2 = h1 + H_ELEMS;            // [131072]

    void* args[] = {(void*)&x, (void*)&Wi, (void*)&Wo, (void*)&Ci, (void*)&Cc,
                    (void*)&h1, (void*)&h2, (void*)&out};
    hipLaunchCooperativeKernel((void*)fused, dim3(512), dim3(256), args, 0, stream);
}

// Round 2
// 289.310 us; speedup vs baseline: 1.5838x; 1.5838x over previous
//
#include <hip/hip_runtime.h>

// ScRRAMBLe layer, multi-kernel pipeline (graph-capturable regular launches).
// R2: cooperative fusion reverted — R1 counters showed (a) hipLaunchCooperativeKernel
// costs ~245 us in this harness (dur 458 vs kernel 213), and (b) at 512 blocks the
// kernel is pure latency-bound (warm replay: 5 MB HBM fetch, still 212 us, VALUBusy 2%,
// occupancy 23%). Fix: keep the 2048-block full-occupancy gemv kernels, and raise
// route_src from 512 to 2048 blocks (each Ci row split across 4 waves, 2 chunks each)
// so the routing scan also runs at 32 waves/CU.
// Compulsory traffic: Wi+Wo (2x128 MiB) + Ci/Cc (2x16 MiB) ~= 44 us @ 6.8 TB/s.

#define N_CORES 512
#define SLOTS 4
#define SLOT_LEN 64
#define CORE_VEC 256                     // SLOTS*SLOT_LEN
#define H_ELEMS (N_CORES * CORE_VEC)     // 131072 floats per h buffer
#define ROW_LEN 2048                     // K*L = 512*4 entries per source row
#define W_CORE (SLOTS * SLOT_LEN * SLOT_LEN)   // 16384 floats per (i,j) weight block

typedef float v4f __attribute__((ext_vector_type(4)));

__device__ __forceinline__ float capped_relu(float v) {
    return fminf(fmaxf(v, 0.0f), 10.0f);
}

// Layer-1 routing at full occupancy: 2048 blocks, wave (row, quarter) owns 2 of the
// 8 chunks of source row `row` (512 Ci entries). For each nonzero count c at dst kl,
// one coalesced 64-lane atomicAdd: h1[kl, lane] += c * x[row, lane].
// Side work: first 512 blocks zero h2 (ordered before gemv_route's atomics by the
// kernel boundary).
__global__ __launch_bounds__(256) void route_src(const float* __restrict__ C,
                                                 const float* __restrict__ src,
                                                 float* __restrict__ h1,
                                                 float* __restrict__ h2) {
    const int gid = blockIdx.x * 256 + threadIdx.x;
    if (gid < H_ELEMS) h2[gid] = 0.0f;

    const int wg = blockIdx.x * 4 + (threadIdx.x >> 6);  // 0..8191
    const int row_id = wg >> 2;                          // source slot ij, 0..2047
    const int quarter = wg & 3;
    const int lane = threadIdx.x & 63;
    const float xv = src[row_id * SLOT_LEN + lane];
    const v4f* row4 = reinterpret_cast<const v4f*>(C + (size_t)row_id * ROW_LEN);

    #pragma unroll
    for (int cc = 0; cc < 2; ++cc) {
        const int chunk = quarter * 2 + cc;
        v4f c4 = __builtin_nontemporal_load(row4 + chunk * 64 + lane);
        #pragma unroll
        for (int q = 0; q < 4; ++q) {
            float cq = c4[q];
            unsigned long long m = __ballot(cq != 0.0f);
            while (m) {
                int L = __ffsll(m) - 1;
                m &= m - 1;
                float c = __shfl(cq, L, 64);
                int dst = chunk * 256 + L * 4 + q;       // kl index
                atomicAdd(h1 + dst * SLOT_LEN + lane, c * xv);
            }
        }
    }
}

// Fused per-core matvec + scatter: y1[i,j,:] = act(Wi[i,j]·h1[i]) staged in LDS,
// then scattered through Cc row (i,j) into h2. Cc row prefetched into registers
// before the W stream so its latency hides under the weight loads.
// W layout [512,4,4,64,64]: wave-contiguous 1 KiB loads, 16-lane shfl_xor reduce.
__global__ __launch_bounds__(256) void gemv_route(const float* __restrict__ W,
                                                  const float* __restrict__ h,
                                                  const float* __restrict__ C2,
                                                  float* __restrict__ h2) {
    __shared__ float ly[SLOT_LEN];
    const int i = blockIdx.x >> 2;
    const int j = blockIdx.x & 3;
    const int t = threadIdx.x & 63;
    const int w = threadIdx.x >> 6;
    const int g = t >> 4;
    const int c16 = t & 15;

    // prefetch this wave's 2 chunks of the Cc routing row (overlaps W stream)
    const float* row = C2 + (size_t)(i * SLOTS + j) * ROW_LEN;
    v4f cpre[2];
    #pragma unroll
    for (int cc = 0; cc < 2; ++cc)
        cpre[cc] = __builtin_nontemporal_load(
            reinterpret_cast<const v4f*>(row) + (w * 2 + cc) * 64 + t);

    v4f hk[SLOTS];
    #pragma unroll
    for (int k = 0; k < SLOTS; ++k)
        hk[k] = *reinterpret_cast<const v4f*>(h + i * CORE_VEC + k * SLOT_LEN + c16 * 4);

    const float* Wb = W + (size_t)(i * SLOTS + j) * W_CORE;

    #pragma unroll
    for (int rr = 0; rr < 4; ++rr) {
        const int r = w * 4 + rr;          // 0..15
        float p = 0.0f;
        #pragma unroll
        for (int k = 0; k < SLOTS; ++k) {
            v4f a = __builtin_nontemporal_load(
                reinterpret_cast<const v4f*>(Wb + k * (SLOT_LEN * SLOT_LEN)
                                             + r * 256 + t * 4));
            p += a.x * hk[k].x + a.y * hk[k].y + a.z * hk[k].z + a.w * hk[k].w;
        }
        p += __shfl_xor(p, 1);
        p += __shfl_xor(p, 2);
        p += __shfl_xor(p, 4);
        p += __shfl_xor(p, 8);
        if (c16 == 0) ly[r * 4 + g] = capped_relu(p);
    }
    __syncthreads();

    const float yv = ly[t];
    #pragma unroll
    for (int cc = 0; cc < 2; ++cc) {
        const int chunk = w * 2 + cc;
        #pragma unroll
        for (int q = 0; q < 4; ++q) {
            float cq = cpre[cc][q];
            unsigned long long m = __ballot(cq != 0.0f);
            while (m) {
                int L = __ffsll(m) - 1;
                m &= m - 1;
                float c = __shfl(cq, L, 64);
                int dst = chunk * 256 + L * 4 + q;
                atomicAdd(h2 + dst * SLOT_LEN + t, c * yv);
            }
        }
    }
}

// Final per-core matvec: out[i,j,:] = act(Wo[i,j]·h2[i]).
__global__ __launch_bounds__(256) void core_gemv(const float* __restrict__ W,
                                                 const float* __restrict__ h,
                                                 float* __restrict__ out) {
    const int i = blockIdx.x >> 2;
    const int j = blockIdx.x & 3;
    const int t = threadIdx.x & 63;
    const int w = threadIdx.x >> 6;
    const int g = t >> 4;
    const int c16 = t & 15;

    v4f hk[SLOTS];
    #pragma unroll
    for (int k = 0; k < SLOTS; ++k)
        hk[k] = *reinterpret_cast<const v4f*>(h + i * CORE_VEC + k * SLOT_LEN + c16 * 4);

    const float* Wb = W + (size_t)(i * SLOTS + j) * W_CORE;

    #pragma unroll
    for (int rr = 0; rr < 4; ++rr) {
        const int r = w * 4 + rr;
        float p = 0.0f;
        #pragma unroll
        for (int k = 0; k < SLOTS; ++k) {
            v4f a = __builtin_nontemporal_load(
                reinterpret_cast<const v4f*>(Wb + k * (SLOT_LEN * SLOT_LEN)
                                             + r * 256 + t * 4));
            p += a.x * hk[k].x + a.y * hk[k].y + a.z * hk[k].z + a.w * hk[k].w;
        }
        p += __shfl_xor(p, 1);
        p += __shfl_xor(p, 2);
        p += __shfl_xor(p, 4);
        p += __shfl_xor(p, 8);
        if (c16 == 0)
            out[(i * SLOTS + j) * SLOT_LEN + r * 4 + g] = capped_relu(p);
    }
}

extern "C" void kernel_launch(void* const* d_in, const int* in_sizes, int n_in,
                              void* d_out, int out_size, void* d_ws, size_t ws_size,
                              hipStream_t stream) {
    const float* x  = (const float*)d_in[0];   // [131072]
    const float* Wi = (const float*)d_in[1];   // [512,4,4,64,64]
    const float* Wo = (const float*)d_in[2];   // [512,4,4,64,64]
    const float* Ci = (const float*)d_in[3];   // [512,4,512,4]
    const float* Cc = (const float*)d_in[4];   // [512,4,512,4]
    float* out = (float*)d_out;                // [512,4,64]

    float* h1 = (float*)d_ws;            // [131072]
    float* h2 = h1 + H_ELEMS;            // [131072]

    // zero only h1; h2 is zeroed as side work inside route_src
    hipMemsetAsync(h1, 0, H_ELEMS * sizeof(float), stream);

    // layer-1 routing: x -> h1 (4 waves per Ci row, full occupancy) + zero h2
    route_src<<<2048, 256, 0, stream>>>(Ci, x, h1, h2);
    // fused: y1 = act(Wi·h1) staged in LDS, scattered through Cc -> h2
    gemv_route<<<2048, 256, 0, stream>>>(Wi, h1, Cc, h2);
    // final matvec: out = act(Wo·h2)
    core_gemv<<<2048, 256, 0, stream>>>(Wo, h2, out);
}